// Round 17
// baseline (900.158 us; speedup 1.0000x reference)
//
#include <hip/hip_runtime.h>
#include <hip/hip_bf16.h>

// Decoder: B=64, T=32, S_ENC=64, E=H=1024, V=32000.
//  - softmax over size-1 axis == 1.0 => ctx[b] = sum_s enc[b,s,:] (attn_W unused)
//  - comb projection batched over all t with ctx appended on K axis (K=3072)
//  - only gates = x W_ih^T + h W_hh^T is sequential; x W_ih^T precomputed.
// Round 17: gemm_s occupancy 4 -> 5 blocks/CU (LDS 5x32=160KB exact fit,
// VGPR 64 <= 102 cap at 5 waves/SIMD -> no spill). Everything else unchanged
// (round-16 config: fused k_prep, lstm_step5+cvt, gemm_p GEMM1).

typedef unsigned short u16;
typedef unsigned int u32;
typedef short s8v __attribute__((ext_vector_type(8)));   // 8 bf16 (4 VGPRs)
typedef float f4v __attribute__((ext_vector_type(4)));   // 16x16 accum

__device__ __forceinline__ u16 f2bf(float f) {
  unsigned x = __float_as_uint(f);
  return (u16)((x + 0x7fffu + ((x >> 16) & 1u)) >> 16);   // RNE
}
__device__ __forceinline__ float bf2f(u16 u) {
  return __uint_as_float(((unsigned)u) << 16);
}

// async 16B global->LDS; lds base must be wave-uniform (HW adds lane*16)
__device__ __forceinline__ void gl_lds16(const void* g, void* l) {
  __builtin_amdgcn_global_load_lds(
      (const __attribute__((address_space(1))) u32*)g,
      (__attribute__((address_space(3))) u32*)l, 16, 0, 0);
}

__device__ __forceinline__ int xcd_swz(int bid, int nb) {
  int q8 = nb >> 3, r8 = nb & 7;
  int xcd = bid & 7, idx = bid >> 3;
  return (xcd < r8 ? xcd * (q8 + 1) : r8 * (q8 + 1) + (xcd - r8) * q8) + idx;
}

// ---------------------------------------------------------------------------
// gemm_s: C = A(bf16,[M][K]) * B(bf16,[N][K])^T + bias. BM=128, BN=NF*32,
// BK=64, 256 thr (4 waves 2x2; wave tile 64 x NF*16), 16+NF*4 KB LDS, XOR
// slot swizzle (0-conflict), gl_lds staging, __launch_bounds__(256,5) ->
// 5 blocks/CU cross-block overlap (VGPR 64 <= 102 cap, no spill).
// EPI: 1 = bf16 out, 2 = bf16 tanh out, 3 = f32 out. K multiple of 64.
// ---------------------------------------------------------------------------
template <int EPI, int NF>
__global__ __launch_bounds__(256, 5) void gemm_s(
    const u16* __restrict__ A, const u16* __restrict__ Bm,
    const float* __restrict__ bias, void* __restrict__ Cp,
    int K, int ldc, int gridM) {
  __shared__ __align__(16) u16 As[128 * 64];        // 16 KB
  __shared__ __align__(16) u16 Bs[NF * 32 * 64];    // NF*4 KB

  int swz = xcd_swz((int)blockIdx.x, (int)gridDim.x);
  int mt = swz % gridM, nt = swz / gridM;   // m-fastest: B-panel L2 reuse
  long bm = (long)mt * 128, bn = (long)nt * (NF * 32);

  int tid = threadIdx.x;
  int w = tid >> 6, l = tid & 63;
  int wm = (w & 1) * 64, wn = (w >> 1) * (NF * 16);
  int lr = l & 15, lg = l >> 4;

  f4v acc[4][NF];
#pragma unroll
  for (int i = 0; i < 4; ++i)
#pragma unroll
    for (int j = 0; j < NF; ++j) acc[i][j] = (f4v){0.f, 0.f, 0.f, 0.f};

  for (int kt = 0; kt < K; kt += 64) {
#pragma unroll
    for (int p = 0; p < 4; ++p) {         // A: 1024 16B chunks
      int cb = p * 256 + w * 64;          // wave-uniform chunk base
      int c = cb + l;
      int row = c >> 3, sp = c & 7;
      int ko = kt + ((sp ^ (row & 7)) << 3);   // pre-swizzled source
      gl_lds16(A + (bm + row) * (long)K + ko, &As[cb * 8]);
    }
#pragma unroll
    for (int p = 0; p < NF; ++p) {        // B: NF*256 chunks
      int cb = p * 256 + w * 64;
      int c = cb + l;
      int row = c >> 3, sp = c & 7;
      int ko = kt + ((sp ^ (row & 7)) << 3);
      gl_lds16(Bm + (bn + row) * (long)K + ko, &Bs[cb * 8]);
    }
    __syncthreads();   // drains vmcnt; other 4 blocks/CU keep the CU busy
#pragma unroll
    for (int ks = 0; ks < 2; ++ks) {
      s8v av[4], bv[NF];
#pragma unroll
      for (int i = 0; i < 4; ++i) {
        int ra = wm + i * 16 + lr;
        int pa = (ks * 4 + lg) ^ (ra & 7);
        av[i] = *(const s8v*)((const char*)&As[0] + ra * 128 + pa * 16);
      }
#pragma unroll
      for (int i = 0; i < NF; ++i) {
        int rb = wn + i * 16 + lr;
        int pb = (ks * 4 + lg) ^ (rb & 7);
        bv[i] = *(const s8v*)((const char*)&Bs[0] + rb * 128 + pb * 16);
      }
      __builtin_amdgcn_s_setprio(1);
#pragma unroll
      for (int mi = 0; mi < 4; ++mi)
#pragma unroll
        for (int ni = 0; ni < NF; ++ni)
          acc[mi][ni] = __builtin_amdgcn_mfma_f32_16x16x32_bf16(
              av[mi], bv[ni], acc[mi][ni], 0, 0, 0);
      __builtin_amdgcn_s_setprio(0);
    }
    __syncthreads();
  }

  // epilogue: C/D layout col=lane&15, row=4*(lane>>4)+reg
#pragma unroll
  for (int mi = 0; mi < 4; ++mi) {
#pragma unroll
    for (int q = 0; q < 4; ++q) {
      long row = bm + wm + mi * 16 + lg * 4 + q;
#pragma unroll
      for (int ni = 0; ni < NF; ++ni) {
        long col = bn + wn + ni * 16 + lr;
        float v = acc[mi][ni][q] + bias[col];
        if (EPI == 2) v = tanhf(v);
        if (EPI == 3)
          ((float*)Cp)[row * (long)ldc + col] = v;
        else
          ((u16*)Cp)[row * (long)ldc + col] = f2bf(v);
      }
    }
  }
}

// ---------------------------------------------------------------------------
// gemm_p (GEMM1): 128x256, 3-slot ring, vmcnt(6). PERM=1: permuted epilogue
// for XPROJ layout [t][b][hcol][gate] (row'=(r&31)*64+(r>>5),
// col'=(c&1023)*4+(c>>10)), ldc fixed 4096.
// ---------------------------------------------------------------------------
template <int EPI, int PERM>
__global__ __launch_bounds__(512, 1) void gemm_p(
    const u16* __restrict__ A, const u16* __restrict__ Bm,
    const float* __restrict__ bias, void* __restrict__ Cp,
    int K, int ldc, int gridM) {
  __shared__ __align__(16) u16 LDS[3 * 24576];

  int swz = xcd_swz((int)blockIdx.x, (int)gridDim.x);
  int mt = swz % gridM, nt = swz / gridM;
  long bm = (long)mt * 128, bn = (long)nt * 256;

  int tid = threadIdx.x;
  int w = tid >> 6, l = tid & 63;
  int wm = w & 1, wn = w >> 1;
  int lr = l & 15, lg = l >> 4;

  int nt_k = K >> 6;

  auto stage = [&](int s, int kt_idx) {
    int kt = kt_idx << 6;
    u16* sa = &LDS[s * 24576];
    u16* sb = &LDS[s * 24576 + 8192];
#pragma unroll
    for (int ch = 0; ch < 2; ++ch) {
      int cb = ch * 512 + w * 64;
      int c = cb + l;
      int row = c >> 3, sp = c & 7;
      gl_lds16(A + (bm + row) * (long)K + kt + ((sp ^ (row & 7)) << 3),
               sa + cb * 8);
    }
#pragma unroll
    for (int ch = 0; ch < 4; ++ch) {
      int cb = ch * 512 + w * 64;
      int c = cb + l;
      int row = c >> 3, sp = c & 7;
      gl_lds16(Bm + (bn + row) * (long)K + kt + ((sp ^ (row & 7)) << 3),
               sb + cb * 8);
    }
  };

  f4v acc[4][4];
#pragma unroll
  for (int i = 0; i < 4; ++i)
#pragma unroll
    for (int j = 0; j < 4; ++j) acc[i][j] = (f4v){0.f, 0.f, 0.f, 0.f};

  stage(0, 0);
  stage(1, 1);
  asm volatile("s_waitcnt vmcnt(6)" ::: "memory");
  __builtin_amdgcn_s_barrier();
  __builtin_amdgcn_sched_barrier(0);

  for (int t = 0; t < nt_k; ++t) {
    if (t + 2 < nt_k) stage((t + 2) % 3, t + 2);
    const u16* sa = &LDS[(t % 3) * 24576];
    const u16* sb = &LDS[(t % 3) * 24576 + 8192];
#pragma unroll
    for (int ks = 0; ks < 2; ++ks) {
      s8v av[4], bv[4];
#pragma unroll
      for (int i = 0; i < 4; ++i) {
        int ra = wm * 64 + i * 16 + lr;
        int pa = (ks * 4 + lg) ^ (ra & 7);
        av[i] = *(const s8v*)((const char*)sa + ra * 128 + pa * 16);
        int rb = wn * 64 + i * 16 + lr;
        int pb = (ks * 4 + lg) ^ (rb & 7);
        bv[i] = *(const s8v*)((const char*)sb + rb * 128 + pb * 16);
      }
      __builtin_amdgcn_s_setprio(1);
#pragma unroll
      for (int mi = 0; mi < 4; ++mi)
#pragma unroll
        for (int ni = 0; ni < 4; ++ni)
          acc[mi][ni] = __builtin_amdgcn_mfma_f32_16x16x32_bf16(
              av[mi], bv[ni], acc[mi][ni], 0, 0, 0);
      __builtin_amdgcn_s_setprio(0);
    }
    if (t + 1 >= nt_k) break;
    if (t + 2 < nt_k) {
      asm volatile("s_waitcnt vmcnt(6)" ::: "memory");
    } else {
      asm volatile("s_waitcnt vmcnt(0)" ::: "memory");
    }
    __builtin_amdgcn_s_barrier();
    __builtin_amdgcn_sched_barrier(0);
  }

#pragma unroll
  for (int mi = 0; mi < 4; ++mi) {
#pragma unroll
    for (int q = 0; q < 4; ++q) {
      long row = bm + wm * 64 + mi * 16 + lg * 4 + q;
#pragma unroll
      for (int ni = 0; ni < 4; ++ni) {
        long col = bn + wn * 64 + ni * 16 + lr;
        float v = acc[mi][ni][q] + bias[col];
        if (PERM) {
          long prow = (row & 31) * 64 + (row >> 5);
          long pcol = (col & 1023) * 4 + (col >> 10);
          ((u16*)Cp)[prow * 4096 + pcol] = f2bf(v);
        } else if (EPI == 3) {
          ((float*)Cp)[row * (long)ldc + col] = v;
        } else {
          ((u16*)Cp)[row * (long)ldc + col] = f2bf(v);
        }
      }
    }
  }
}

// ---------------------------------------------------------------------------
// Fallback GEMM with f32 B (in-kernel convert) if ws can't hold bf16 copies.
// ---------------------------------------------------------------------------
template <int EPI, int PERM>
__global__ __launch_bounds__(256, 2) void gemm_btf(
    const u16* __restrict__ A, const float* __restrict__ Bm,
    const float* __restrict__ bias, void* __restrict__ Cp,
    int K, int ldc, int gridM) {
  __shared__ __align__(16) u16 As[128][72];
  __shared__ __align__(16) u16 Bs[128][72];
  int swz = xcd_swz((int)blockIdx.x, (int)gridDim.x);
  int mt = swz % gridM, nt = swz / gridM;
  long bm = (long)mt * 128, bn = (long)nt * 128;
  int tid = threadIdx.x;
  int w = tid >> 6, l = tid & 63;
  int wm = (w & 1) * 64, wn = (w >> 1) * 64;
  int lr = l & 15, lg = l >> 4;
  f4v acc[4][4];
#pragma unroll
  for (int i = 0; i < 4; ++i)
#pragma unroll
    for (int j = 0; j < 4; ++j) acc[i][j] = (f4v){0.f, 0.f, 0.f, 0.f};
  for (int kt = 0; kt < K; kt += 64) {
#pragma unroll
    for (int p = 0; p < 4; ++p) {
      int ch = p * 256 + tid;
      int row = ch >> 3, cc = ch & 7;
      *(uint4*)((char*)(&As[0][0]) + row * 144 + cc * 16) =
          *(const uint4*)(A + (bm + row) * (long)K + kt + cc * 8);
      const float* bp = Bm + (bn + row) * (long)K + kt + cc * 8;
      float4 b0 = *(const float4*)bp;
      float4 b1 = *(const float4*)(bp + 4);
      union { u16 t8[8]; uint4 v; } cv;
      cv.t8[0] = f2bf(b0.x); cv.t8[1] = f2bf(b0.y);
      cv.t8[2] = f2bf(b0.z); cv.t8[3] = f2bf(b0.w);
      cv.t8[4] = f2bf(b1.x); cv.t8[5] = f2bf(b1.y);
      cv.t8[6] = f2bf(b1.z); cv.t8[7] = f2bf(b1.w);
      *(uint4*)((char*)(&Bs[0][0]) + row * 144 + cc * 16) = cv.v;
    }
    __syncthreads();
#pragma unroll
    for (int ks = 0; ks < 2; ++ks) {
      int kb = ks * 64 + lg * 16;
      s8v av[4], bv[4];
#pragma unroll
      for (int i = 0; i < 4; ++i) {
        av[i] = *(const s8v*)((const char*)(&As[0][0]) + (wm + i * 16 + lr) * 144 + kb);
        bv[i] = *(const s8v*)((const char*)(&Bs[0][0]) + (wn + i * 16 + lr) * 144 + kb);
      }
#pragma unroll
      for (int mi = 0; mi < 4; ++mi)
#pragma unroll
        for (int ni = 0; ni < 4; ++ni)
          acc[mi][ni] = __builtin_amdgcn_mfma_f32_16x16x32_bf16(
              av[mi], bv[ni], acc[mi][ni], 0, 0, 0);
    }
    __syncthreads();
  }
#pragma unroll
  for (int mi = 0; mi < 4; ++mi) {
#pragma unroll
    for (int q = 0; q < 4; ++q) {
      long row = bm + wm + mi * 16 + lg * 4 + q;
#pragma unroll
      for (int ni = 0; ni < 4; ++ni) {
        long col = bn + wn + ni * 16 + lr;
        float v = acc[mi][ni][q] + bias[col];
        if (EPI == 2) v = tanhf(v);
        if (PERM) {
          long prow = (row & 31) * 64 + (row >> 5);
          long pcol = (col & 1023) * 4 + (col >> 10);
          ((u16*)Cp)[prow * 4096 + pcol] = f2bf(v);
        } else if (EPI == 3) {
          ((float*)Cp)[row * (long)ldc + col] = v;
        } else {
          ((u16*)Cp)[row * (long)ldc + col] = f2bf(v);
        }
      }
    }
  }
}

// ---------------------------------------------------------------------------
// lstm_step5 + fused outW cvt slice on blocks 256..511 (round-15, proven).
// H2 layout: [s=k>>3][batch 0..63][8]. W2 layout: [j][s][r=g*8+cc][8].
// ---------------------------------------------------------------------------
__global__ __launch_bounds__(256, 1) void lstm_step5(
    const u16* __restrict__ W2, const u16* __restrict__ xprojT,
    const u16* __restrict__ h2_in, u16* __restrict__ h2_next,
    float* __restrict__ c_buf, u16* __restrict__ a2,
    float* __restrict__ hf, float* __restrict__ cf, int t,
    const float* __restrict__ cvt_src, u16* __restrict__ cvt_dst,
    int cvt_base, int cvt_n) {
  __shared__ float Gs[32][33];

  int bid = blockIdx.x;
  if (bid >= 256) {
    if (cvt_n > 0) {
      int base = cvt_base + (bid - 256) * 500;
      for (int i = threadIdx.x; i < 500; i += 256) {
        long g = base + i;
        const float* s = cvt_src + g * 8;
        float4 a = *(const float4*)s, b = *(const float4*)(s + 4);
        union { u16 t8[8]; uint4 v; } cv;
        cv.t8[0] = f2bf(a.x); cv.t8[1] = f2bf(a.y);
        cv.t8[2] = f2bf(a.z); cv.t8[3] = f2bf(a.w);
        cv.t8[4] = f2bf(b.x); cv.t8[5] = f2bf(b.y);
        cv.t8[6] = f2bf(b.z); cv.t8[7] = f2bf(b.w);
        *(uint4*)(cvt_dst + g * 8) = cv.v;
      }
    }
    return;
  }

  int j = bid & 127, bh = bid >> 7;
  int tid = threadIdx.x, w = tid >> 6, l = tid & 63;
  int bq = w & 1, nh = w >> 1;
  int lr = l & 15, lg = l >> 4;

  const u16* aptr = h2_in + lg * 512 + (bh * 32 + bq * 16 + lr) * 8;
  const u16* bptr = W2 + (long)j * 32768 + lg * 256 + (nh * 16 + lr) * 8;

  int eb = tid >> 3, er = tid & 7;
  int gb = bh * 32 + eb, ecol = j * 8 + er;
  uint2 xv = *(const uint2*)(xprojT + ((long)t * 64 + gb) * 4096 + ecol * 4);
  float co = c_buf[gb * 1024 + ecol];

  f4v acc0 = {0.f, 0.f, 0.f, 0.f}, acc1 = {0.f, 0.f, 0.f, 0.f};
  f4v acc2 = {0.f, 0.f, 0.f, 0.f}, acc3 = {0.f, 0.f, 0.f, 0.f};
#pragma unroll
  for (int kc = 0; kc < 32; kc += 4) {
    s8v a0 = *(const s8v*)(aptr + (kc + 0) * 2048);
    s8v b0 = *(const s8v*)(bptr + (kc + 0) * 1024);
    s8v a1 = *(const s8v*)(aptr + (kc + 1) * 2048);
    s8v b1 = *(const s8v*)(bptr + (kc + 1) * 1024);
    s8v a2r = *(const s8v*)(aptr + (kc + 2) * 2048);
    s8v b2 = *(const s8v*)(bptr + (kc + 2) * 1024);
    s8v a3 = *(const s8v*)(aptr + (kc + 3) * 2048);
    s8v b3 = *(const s8v*)(bptr + (kc + 3) * 1024);
    acc0 = __builtin_amdgcn_mfma_f32_16x16x32_bf16(a0, b0, acc0, 0, 0, 0);
    acc1 = __builtin_amdgcn_mfma_f32_16x16x32_bf16(a1, b1, acc1, 0, 0, 0);
    acc2 = __builtin_amdgcn_mfma_f32_16x16x32_bf16(a2r, b2, acc2, 0, 0, 0);
    acc3 = __builtin_amdgcn_mfma_f32_16x16x32_bf16(a3, b3, acc3, 0, 0, 0);
  }
#pragma unroll
  for (int q = 0; q < 4; ++q)
    Gs[bq * 16 + lg * 4 + q][nh * 16 + lr] =
        acc0[q] + acc1[q] + acc2[q] + acc3[q];
  __syncthreads();

  float pi = Gs[eb][er]      + bf2f((u16)(xv.x));
  float pf = Gs[eb][8 + er]  + bf2f((u16)(xv.x >> 16));
  float pg = Gs[eb][16 + er] + bf2f((u16)(xv.y));
  float po = Gs[eb][24 + er] + bf2f((u16)(xv.y >> 16));
  float iv = 1.f / (1.f + expf(-pi));
  float fv = 1.f / (1.f + expf(-pf));
  float ov = 1.f / (1.f + expf(-po));
  float gv = tanhf(pg);
  float cn = fv * co + iv * gv;
  float hn = ov * tanhf(cn);
  c_buf[gb * 1024 + ecol] = cn;
  u16 hb = f2bf(hn);
  h2_next[j * 512 + bh * 256 + tid] = hb;   // H2 layout, contiguous per block
  a2[(long)(gb * 32 + t) * 3072 + ecol] = hb;
  if (t == 31) {
    hf[gb * 1024 + ecol] = hn;
    cf[gb * 1024 + ecol] = cn;
  }
}

// ---------------------------------------------------------------------------
// k_prep: ALL independent prep work in ONE launch (6976 blocks x 256 thr).
// ---------------------------------------------------------------------------
__global__ void k_prep(
    const float* __restrict__ bih, const float* __restrict__ bhh,
    const float* __restrict__ h0, const float* __restrict__ c0,
    const int* __restrict__ inputs, const float* __restrict__ emb,
    const float* __restrict__ enc, const float* __restrict__ Whh,
    const float* __restrict__ Wih, const float* __restrict__ combW,
    float* __restrict__ bias, u16* __restrict__ h2buf0,
    float* __restrict__ cbuf, u16* __restrict__ W2,
    u16* __restrict__ EMBX, u16* __restrict__ A2,
    u16* __restrict__ WIH_BF, u16* __restrict__ COMBW_BF, int haveW1) {
  int bid = blockIdx.x, tid = threadIdx.x;
  if (bid < 2048) {
    int idx = bid * 256 + tid;              // 524288 = 4096 rows x 128 s
    int row = idx >> 7, s = idx & 127;
    int g = row >> 10, rr = row & 1023;
    int j = rr >> 3, cc = rr & 7;
    const float* src = Whh + (long)row * 1024 + s * 8;
    float4 a = *(const float4*)src, b = *(const float4*)(src + 4);
    union { u16 t[8]; uint4 v; } cv;
    cv.t[0] = f2bf(a.x); cv.t[1] = f2bf(a.y); cv.t[2] = f2bf(a.z); cv.t[3] = f2bf(a.w);
    cv.t[4] = f2bf(b.x); cv.t[5] = f2bf(b.y); cv.t[6] = f2bf(b.z); cv.t[7] = f2bf(b.w);
    *(uint4*)(W2 + ((((long)j * 128 + s) * 32) + g * 8 + cc) * 8) = cv.v;
  } else if (bid < 4096) {
    if (!haveW1) return;
    int i = (bid - 2048) * 256 + tid;       // 524288 groups
    const float4* s = (const float4*)(Wih + (long)i * 8);
    float4 a = s[0], b = s[1];
    union { u16 t[8]; uint4 v; } cv;
    cv.t[0] = f2bf(a.x); cv.t[1] = f2bf(a.y); cv.t[2] = f2bf(a.z); cv.t[3] = f2bf(a.w);
    cv.t[4] = f2bf(b.x); cv.t[5] = f2bf(b.y); cv.t[6] = f2bf(b.z); cv.t[7] = f2bf(b.w);
    ((uint4*)WIH_BF)[i] = cv.v;
  } else if (bid < 5632) {
    if (!haveW1) return;
    int i = (bid - 4096) * 256 + tid;       // 393216 groups
    const float4* s = (const float4*)(combW + (long)i * 8);
    float4 a = s[0], b = s[1];
    union { u16 t[8]; uint4 v; } cv;
    cv.t[0] = f2bf(a.x); cv.t[1] = f2bf(a.y); cv.t[2] = f2bf(a.z); cv.t[3] = f2bf(a.w);
    cv.t[4] = f2bf(b.x); cv.t[5] = f2bf(b.y); cv.t[6] = f2bf(b.z); cv.t[7] = f2bf(b.w);
    ((uint4*)COMBW_BF)[i] = cv.v;
  } else if (bid < 6656) {
    int i = (bid - 5632) * 256 + tid;       // 262144 groups
    int r = i >> 7, k8 = (i & 127) * 8;
    const float* s = emb + (long)inputs[r] * 1024 + k8;
    float4 a = *(const float4*)s, b = *(const float4*)(s + 4);
    union { u16 t[8]; uint4 v; } cv;
    cv.t[0] = f2bf(a.x); cv.t[1] = f2bf(a.y); cv.t[2] = f2bf(a.z); cv.t[3] = f2bf(a.w);
    cv.t[4] = f2bf(b.x); cv.t[5] = f2bf(b.y); cv.t[6] = f2bf(b.z); cv.t[7] = f2bf(b.w);
    ((uint4*)EMBX)[i] = cv.v;
  } else if (bid < 6720) {
    int b = bid - 6656;                     // 64 batches
    int dg = tid;
    float s[8] = {0.f, 0.f, 0.f, 0.f, 0.f, 0.f, 0.f, 0.f};
    for (int si = 0; si < 64; ++si) {
      const float* p = enc + ((long)(b * 64 + si)) * 2048 + dg * 8;
      float4 x = *(const float4*)p, y = *(const float4*)(p + 4);
      s[0] += x.x; s[1] += x.y; s[2] += x.z; s[3] += x.w;
      s[4] += y.x; s[5] += y.y; s[6] += y.z; s[7] += y.w;
    }
    union { u16 t[8]; uint4 v; } cv;
#pragma unroll
    for (int e = 0; e < 8; ++e) cv.t[e] = f2bf(s[e]);
    for (int t2 = 0; t2 < 32; ++t2)
      *(uint4*)(A2 + (long)(b * 32 + t2) * 3072 + 1024 + dg * 8) = cv.v;
  } else {
    int i = (bid - 6720) * 256 + tid;       // 65536
    if (i < 4096) bias[i] = bih[i] + bhh[i];
    int b = i >> 10, col = i & 1023;
    h2buf0[(col >> 3) * 512 + b * 8 + (col & 7)] = f2bf(h0[i]);
    cbuf[i] = c0[i];
  }
}

// ---------------------------------------------------------------------------
extern "C" void kernel_launch(void* const* d_in, const int* in_sizes, int n_in,
                              void* d_out, int out_size, void* d_ws, size_t ws_size,
                              hipStream_t stream) {
  (void)in_sizes; (void)n_in; (void)out_size;
  const int*   inputs = (const int*)d_in[0];
  const float* enc    = (const float*)d_in[1];
  const float* h0     = (const float*)d_in[2];
  const float* c0     = (const float*)d_in[3];
  const float* emb    = (const float*)d_in[4];
  const float* Wih    = (const float*)d_in[5];
  const float* Whh    = (const float*)d_in[6];
  const float* bih    = (const float*)d_in[7];
  const float* bhh    = (const float*)d_in[8];
  // d_in[9] = attn_W: unused (softmax over size-1 axis == all ones)
  const float* combW  = (const float*)d_in[10];
  const float* combb  = (const float*)d_in[11];
  const float* outW   = (const float*)d_in[12];
  const float* outb   = (const float*)d_in[13];
  float* out = (float*)d_out;

  char* ws = (char*)d_ws;
  size_t off = 0;
  auto alloc = [&](size_t bytes) {
    char* p = ws + off;
    off += (bytes + 255) & ~(size_t)255;
    return p;
  };
  u16*   W2     = (u16*)  alloc(4096ull * 1024 * 2);   // Whh fragment layout
  u16*   XPROJ  = (u16*)  alloc(2048ull * 4096 * 2);   // [t][b][hcol][gate]
  u16*   EMBX   = (u16*)  alloc(2048ull * 1024 * 2);
  u16*   A2     = (u16*)  alloc(2048ull * 3072 * 2);
  u16*   OUTS   = (u16*)  alloc(2048ull * 1024 * 2);
  float* BIAS   = (float*)alloc(4096 * 4);
  u16*   H2BUF  = (u16*)  alloc(2ull * 65536 * 2);     // h ping-pong (H2 layout)
  float* CBUF   = (float*)alloc(65536 * 4);
  u16*   WIH_BF   = (u16*)alloc(4096ull * 1024 * 2);
  u16*   COMBW_BF = (u16*)alloc(1024ull * 3072 * 2);
  size_t off_w1 = off;
  u16*   OUTW_BF  = (u16*)alloc(32000ull * 1024 * 2);
  size_t off_w2 = off;                                 // ~127 MB
  bool haveW1 = ws_size >= off_w1;
  bool haveW2 = ws_size >= off_w2;

  // ONE fused prep launch (Whh/Wih/combW converts, emb, ctx, bias/h0/c0)
  k_prep<<<dim3(6976), dim3(256), 0, stream>>>(
      bih, bhh, h0, c0, inputs, emb, enc, Whh, Wih, combW,
      BIAS, H2BUF, CBUF, W2, EMBX, A2, WIH_BF, COMBW_BF, haveW1 ? 1 : 0);

  // GEMM1: XPROJ (permuted layout) = EMBX @ W_ih^T + (b_ih+b_hh)
  if (haveW1)
    gemm_p<1, 1><<<dim3(256), dim3(512), 0, stream>>>(EMBX, WIH_BF, BIAS, XPROJ,
                                                      1024, 4096, 16);
  else
    gemm_btf<1, 1><<<dim3(512), dim3(256), 0, stream>>>(EMBX, Wih, BIAS, XPROJ,
                                                        1024, 4096, 16);

  // 32 sequential LSTM steps; blocks 256..511 convert outW slice t
  for (int t = 0; t < 32; ++t) {
    u16* hin  = H2BUF + (t & 1) * 65536;
    u16* hout = H2BUF + ((t + 1) & 1) * 65536;
    lstm_step5<<<dim3(512), dim3(256), 0, stream>>>(
        W2, XPROJ, hin, hout, CBUF, A2,
        out + 65536000, out + 65536000 + 65536, t,
        outW, OUTW_BF, t * 128000, haveW2 ? 128000 : 0);
  }

  // GEMM2: OUTS = tanh([h_seq|ctx] @ comb_W^T + comb_b)  (K=3072, BN=64)
  if (haveW1)
    gemm_s<2, 2><<<dim3(256), dim3(256), 0, stream>>>(A2, COMBW_BF, combb, OUTS,
                                                      3072, 1024, 16);
  else
    gemm_btf<2, 0><<<dim3(128), dim3(256), 0, stream>>>(A2, combW, combb, OUTS,
                                                        3072, 1024, 16);
  // GEMM3: logits = OUTS @ out_W^T + out_b  (128x128, 5 blocks/CU)
  if (haveW2)
    gemm_s<3, 4><<<dim3(4000), dim3(256), 0, stream>>>(OUTS, OUTW_BF, outb, d_out,
                                                       1024, 32000, 16);
  else
    gemm_btf<3, 0><<<dim3(4000), dim3(256), 0, stream>>>(OUTS, outW, outb, d_out,
                                                         1024, 32000, 16);
}

// Round 18
// 517.821 us; speedup vs baseline: 1.7384x; 1.7384x over previous
//
#include <hip/hip_runtime.h>
#include <hip/hip_bf16.h>

// Decoder: B=64, T=32, S_ENC=64, E=H=1024, V=32000.
//  - softmax over size-1 axis == 1.0 => ctx[b] = sum_s enc[b,s,:] (attn_W unused)
//  - comb projection batched over all t with ctx appended on K axis (K=3072)
//  - only gates = x W_ih^T + h W_hh^T is sequential; x W_ih^T precomputed.
// Round 18: FINAL = round-16 config exactly (518us, best measured).
// Round-17's (256,5) occupancy bump forced 48-VGPR allocation -> spill
// (WRITE 881MB, MfmaUtil 9.8%); 64-VGPR accumulators require the 4-block cap.

typedef unsigned short u16;
typedef unsigned int u32;
typedef short s8v __attribute__((ext_vector_type(8)));   // 8 bf16 (4 VGPRs)
typedef float f4v __attribute__((ext_vector_type(4)));   // 16x16 accum

__device__ __forceinline__ u16 f2bf(float f) {
  unsigned x = __float_as_uint(f);
  return (u16)((x + 0x7fffu + ((x >> 16) & 1u)) >> 16);   // RNE
}
__device__ __forceinline__ float bf2f(u16 u) {
  return __uint_as_float(((unsigned)u) << 16);
}

// async 16B global->LDS; lds base must be wave-uniform (HW adds lane*16)
__device__ __forceinline__ void gl_lds16(const void* g, void* l) {
  __builtin_amdgcn_global_load_lds(
      (const __attribute__((address_space(1))) u32*)g,
      (__attribute__((address_space(3))) u32*)l, 16, 0, 0);
}

__device__ __forceinline__ int xcd_swz(int bid, int nb) {
  int q8 = nb >> 3, r8 = nb & 7;
  int xcd = bid & 7, idx = bid >> 3;
  return (xcd < r8 ? xcd * (q8 + 1) : r8 * (q8 + 1) + (xcd - r8) * q8) + idx;
}

// ---------------------------------------------------------------------------
// gemm_s: C = A(bf16,[M][K]) * B(bf16,[N][K])^T + bias. BM=128, BN=NF*32,
// BK=64, 256 thr (4 waves 2x2; wave tile 64 x NF*16), 16+NF*4 KB LDS, XOR
// slot swizzle (0-conflict), gl_lds staging, __launch_bounds__(256,4) ->
// 4 blocks/CU cross-block overlap (64 VGPR, no spill; (256,5) spills).
// EPI: 1 = bf16 out, 2 = bf16 tanh out, 3 = f32 out. K multiple of 64.
// ---------------------------------------------------------------------------
template <int EPI, int NF>
__global__ __launch_bounds__(256, 4) void gemm_s(
    const u16* __restrict__ A, const u16* __restrict__ Bm,
    const float* __restrict__ bias, void* __restrict__ Cp,
    int K, int ldc, int gridM) {
  __shared__ __align__(16) u16 As[128 * 64];        // 16 KB
  __shared__ __align__(16) u16 Bs[NF * 32 * 64];    // NF*4 KB

  int swz = xcd_swz((int)blockIdx.x, (int)gridDim.x);
  int mt = swz % gridM, nt = swz / gridM;   // m-fastest: B-panel L2 reuse
  long bm = (long)mt * 128, bn = (long)nt * (NF * 32);

  int tid = threadIdx.x;
  int w = tid >> 6, l = tid & 63;
  int wm = (w & 1) * 64, wn = (w >> 1) * (NF * 16);
  int lr = l & 15, lg = l >> 4;

  f4v acc[4][NF];
#pragma unroll
  for (int i = 0; i < 4; ++i)
#pragma unroll
    for (int j = 0; j < NF; ++j) acc[i][j] = (f4v){0.f, 0.f, 0.f, 0.f};

  for (int kt = 0; kt < K; kt += 64) {
#pragma unroll
    for (int p = 0; p < 4; ++p) {         // A: 1024 16B chunks
      int cb = p * 256 + w * 64;          // wave-uniform chunk base
      int c = cb + l;
      int row = c >> 3, sp = c & 7;
      int ko = kt + ((sp ^ (row & 7)) << 3);   // pre-swizzled source
      gl_lds16(A + (bm + row) * (long)K + ko, &As[cb * 8]);
    }
#pragma unroll
    for (int p = 0; p < NF; ++p) {        // B: NF*256 chunks
      int cb = p * 256 + w * 64;
      int c = cb + l;
      int row = c >> 3, sp = c & 7;
      int ko = kt + ((sp ^ (row & 7)) << 3);
      gl_lds16(Bm + (bn + row) * (long)K + ko, &Bs[cb * 8]);
    }
    __syncthreads();   // drains vmcnt; other 3 blocks/CU keep the CU busy
#pragma unroll
    for (int ks = 0; ks < 2; ++ks) {
      s8v av[4], bv[NF];
#pragma unroll
      for (int i = 0; i < 4; ++i) {
        int ra = wm + i * 16 + lr;
        int pa = (ks * 4 + lg) ^ (ra & 7);
        av[i] = *(const s8v*)((const char*)&As[0] + ra * 128 + pa * 16);
      }
#pragma unroll
      for (int i = 0; i < NF; ++i) {
        int rb = wn + i * 16 + lr;
        int pb = (ks * 4 + lg) ^ (rb & 7);
        bv[i] = *(const s8v*)((const char*)&Bs[0] + rb * 128 + pb * 16);
      }
      __builtin_amdgcn_s_setprio(1);
#pragma unroll
      for (int mi = 0; mi < 4; ++mi)
#pragma unroll
        for (int ni = 0; ni < NF; ++ni)
          acc[mi][ni] = __builtin_amdgcn_mfma_f32_16x16x32_bf16(
              av[mi], bv[ni], acc[mi][ni], 0, 0, 0);
      __builtin_amdgcn_s_setprio(0);
    }
    __syncthreads();
  }

  // epilogue: C/D layout col=lane&15, row=4*(lane>>4)+reg
#pragma unroll
  for (int mi = 0; mi < 4; ++mi) {
#pragma unroll
    for (int q = 0; q < 4; ++q) {
      long row = bm + wm + mi * 16 + lg * 4 + q;
#pragma unroll
      for (int ni = 0; ni < NF; ++ni) {
        long col = bn + wn + ni * 16 + lr;
        float v = acc[mi][ni][q] + bias[col];
        if (EPI == 2) v = tanhf(v);
        if (EPI == 3)
          ((float*)Cp)[row * (long)ldc + col] = v;
        else
          ((u16*)Cp)[row * (long)ldc + col] = f2bf(v);
      }
    }
  }
}

// ---------------------------------------------------------------------------
// gemm_p (GEMM1): 128x256, 3-slot ring, vmcnt(6). PERM=1: permuted epilogue
// for XPROJ layout [t][b][hcol][gate] (row'=(r&31)*64+(r>>5),
// col'=(c&1023)*4+(c>>10)), ldc fixed 4096.
// ---------------------------------------------------------------------------
template <int EPI, int PERM>
__global__ __launch_bounds__(512, 1) void gemm_p(
    const u16* __restrict__ A, const u16* __restrict__ Bm,
    const float* __restrict__ bias, void* __restrict__ Cp,
    int K, int ldc, int gridM) {
  __shared__ __align__(16) u16 LDS[3 * 24576];

  int swz = xcd_swz((int)blockIdx.x, (int)gridDim.x);
  int mt = swz % gridM, nt = swz / gridM;
  long bm = (long)mt * 128, bn = (long)nt * 256;

  int tid = threadIdx.x;
  int w = tid >> 6, l = tid & 63;
  int wm = w & 1, wn = w >> 1;
  int lr = l & 15, lg = l >> 4;

  int nt_k = K >> 6;

  auto stage = [&](int s, int kt_idx) {
    int kt = kt_idx << 6;
    u16* sa = &LDS[s * 24576];
    u16* sb = &LDS[s * 24576 + 8192];
#pragma unroll
    for (int ch = 0; ch < 2; ++ch) {
      int cb = ch * 512 + w * 64;
      int c = cb + l;
      int row = c >> 3, sp = c & 7;
      gl_lds16(A + (bm + row) * (long)K + kt + ((sp ^ (row & 7)) << 3),
               sa + cb * 8);
    }
#pragma unroll
    for (int ch = 0; ch < 4; ++ch) {
      int cb = ch * 512 + w * 64;
      int c = cb + l;
      int row = c >> 3, sp = c & 7;
      gl_lds16(Bm + (bn + row) * (long)K + kt + ((sp ^ (row & 7)) << 3),
               sb + cb * 8);
    }
  };

  f4v acc[4][4];
#pragma unroll
  for (int i = 0; i < 4; ++i)
#pragma unroll
    for (int j = 0; j < 4; ++j) acc[i][j] = (f4v){0.f, 0.f, 0.f, 0.f};

  stage(0, 0);
  stage(1, 1);
  asm volatile("s_waitcnt vmcnt(6)" ::: "memory");
  __builtin_amdgcn_s_barrier();
  __builtin_amdgcn_sched_barrier(0);

  for (int t = 0; t < nt_k; ++t) {
    if (t + 2 < nt_k) stage((t + 2) % 3, t + 2);
    const u16* sa = &LDS[(t % 3) * 24576];
    const u16* sb = &LDS[(t % 3) * 24576 + 8192];
#pragma unroll
    for (int ks = 0; ks < 2; ++ks) {
      s8v av[4], bv[4];
#pragma unroll
      for (int i = 0; i < 4; ++i) {
        int ra = wm * 64 + i * 16 + lr;
        int pa = (ks * 4 + lg) ^ (ra & 7);
        av[i] = *(const s8v*)((const char*)sa + ra * 128 + pa * 16);
        int rb = wn * 64 + i * 16 + lr;
        int pb = (ks * 4 + lg) ^ (rb & 7);
        bv[i] = *(const s8v*)((const char*)sb + rb * 128 + pb * 16);
      }
      __builtin_amdgcn_s_setprio(1);
#pragma unroll
      for (int mi = 0; mi < 4; ++mi)
#pragma unroll
        for (int ni = 0; ni < 4; ++ni)
          acc[mi][ni] = __builtin_amdgcn_mfma_f32_16x16x32_bf16(
              av[mi], bv[ni], acc[mi][ni], 0, 0, 0);
      __builtin_amdgcn_s_setprio(0);
    }
    if (t + 1 >= nt_k) break;
    if (t + 2 < nt_k) {
      asm volatile("s_waitcnt vmcnt(6)" ::: "memory");
    } else {
      asm volatile("s_waitcnt vmcnt(0)" ::: "memory");
    }
    __builtin_amdgcn_s_barrier();
    __builtin_amdgcn_sched_barrier(0);
  }

#pragma unroll
  for (int mi = 0; mi < 4; ++mi) {
#pragma unroll
    for (int q = 0; q < 4; ++q) {
      long row = bm + wm * 64 + mi * 16 + lg * 4 + q;
#pragma unroll
      for (int ni = 0; ni < 4; ++ni) {
        long col = bn + wn * 64 + ni * 16 + lr;
        float v = acc[mi][ni][q] + bias[col];
        if (PERM) {
          long prow = (row & 31) * 64 + (row >> 5);
          long pcol = (col & 1023) * 4 + (col >> 10);
          ((u16*)Cp)[prow * 4096 + pcol] = f2bf(v);
        } else if (EPI == 3) {
          ((float*)Cp)[row * (long)ldc + col] = v;
        } else {
          ((u16*)Cp)[row * (long)ldc + col] = f2bf(v);
        }
      }
    }
  }
}

// ---------------------------------------------------------------------------
// Fallback GEMM with f32 B (in-kernel convert) if ws can't hold bf16 copies.
// ---------------------------------------------------------------------------
template <int EPI, int PERM>
__global__ __launch_bounds__(256, 2) void gemm_btf(
    const u16* __restrict__ A, const float* __restrict__ Bm,
    const float* __restrict__ bias, void* __restrict__ Cp,
    int K, int ldc, int gridM) {
  __shared__ __align__(16) u16 As[128][72];
  __shared__ __align__(16) u16 Bs[128][72];
  int swz = xcd_swz((int)blockIdx.x, (int)gridDim.x);
  int mt = swz % gridM, nt = swz / gridM;
  long bm = (long)mt * 128, bn = (long)nt * 128;
  int tid = threadIdx.x;
  int w = tid >> 6, l = tid & 63;
  int wm = (w & 1) * 64, wn = (w >> 1) * 64;
  int lr = l & 15, lg = l >> 4;
  f4v acc[4][4];
#pragma unroll
  for (int i = 0; i < 4; ++i)
#pragma unroll
    for (int j = 0; j < 4; ++j) acc[i][j] = (f4v){0.f, 0.f, 0.f, 0.f};
  for (int kt = 0; kt < K; kt += 64) {
#pragma unroll
    for (int p = 0; p < 4; ++p) {
      int ch = p * 256 + tid;
      int row = ch >> 3, cc = ch & 7;
      *(uint4*)((char*)(&As[0][0]) + row * 144 + cc * 16) =
          *(const uint4*)(A + (bm + row) * (long)K + kt + cc * 8);
      const float* bp = Bm + (bn + row) * (long)K + kt + cc * 8;
      float4 b0 = *(const float4*)bp;
      float4 b1 = *(const float4*)(bp + 4);
      union { u16 t8[8]; uint4 v; } cv;
      cv.t8[0] = f2bf(b0.x); cv.t8[1] = f2bf(b0.y);
      cv.t8[2] = f2bf(b0.z); cv.t8[3] = f2bf(b0.w);
      cv.t8[4] = f2bf(b1.x); cv.t8[5] = f2bf(b1.y);
      cv.t8[6] = f2bf(b1.z); cv.t8[7] = f2bf(b1.w);
      *(uint4*)((char*)(&Bs[0][0]) + row * 144 + cc * 16) = cv.v;
    }
    __syncthreads();
#pragma unroll
    for (int ks = 0; ks < 2; ++ks) {
      int kb = ks * 64 + lg * 16;
      s8v av[4], bv[4];
#pragma unroll
      for (int i = 0; i < 4; ++i) {
        av[i] = *(const s8v*)((const char*)(&As[0][0]) + (wm + i * 16 + lr) * 144 + kb);
        bv[i] = *(const s8v*)((const char*)(&Bs[0][0]) + (wn + i * 16 + lr) * 144 + kb);
      }
#pragma unroll
      for (int mi = 0; mi < 4; ++mi)
#pragma unroll
        for (int ni = 0; ni < 4; ++ni)
          acc[mi][ni] = __builtin_amdgcn_mfma_f32_16x16x32_bf16(
              av[mi], bv[ni], acc[mi][ni], 0, 0, 0);
    }
    __syncthreads();
  }
#pragma unroll
  for (int mi = 0; mi < 4; ++mi) {
#pragma unroll
    for (int q = 0; q < 4; ++q) {
      long row = bm + wm + mi * 16 + lg * 4 + q;
#pragma unroll
      for (int ni = 0; ni < 4; ++ni) {
        long col = bn + wn + ni * 16 + lr;
        float v = acc[mi][ni][q] + bias[col];
        if (EPI == 2) v = tanhf(v);
        if (PERM) {
          long prow = (row & 31) * 64 + (row >> 5);
          long pcol = (col & 1023) * 4 + (col >> 10);
          ((u16*)Cp)[prow * 4096 + pcol] = f2bf(v);
        } else if (EPI == 3) {
          ((float*)Cp)[row * (long)ldc + col] = v;
        } else {
          ((u16*)Cp)[row * (long)ldc + col] = f2bf(v);
        }
      }
    }
  }
}

// ---------------------------------------------------------------------------
// lstm_step5 + fused outW cvt slice on blocks 256..511 (round-15, proven).
// H2 layout: [s=k>>3][batch 0..63][8]. W2 layout: [j][s][r=g*8+cc][8].
// ---------------------------------------------------------------------------
__global__ __launch_bounds__(256, 1) void lstm_step5(
    const u16* __restrict__ W2, const u16* __restrict__ xprojT,
    const u16* __restrict__ h2_in, u16* __restrict__ h2_next,
    float* __restrict__ c_buf, u16* __restrict__ a2,
    float* __restrict__ hf, float* __restrict__ cf, int t,
    const float* __restrict__ cvt_src, u16* __restrict__ cvt_dst,
    int cvt_base, int cvt_n) {
  __shared__ float Gs[32][33];

  int bid = blockIdx.x;
  if (bid >= 256) {
    if (cvt_n > 0) {
      int base = cvt_base + (bid - 256) * 500;
      for (int i = threadIdx.x; i < 500; i += 256) {
        long g = base + i;
        const float* s = cvt_src + g * 8;
        float4 a = *(const float4*)s, b = *(const float4*)(s + 4);
        union { u16 t8[8]; uint4 v; } cv;
        cv.t8[0] = f2bf(a.x); cv.t8[1] = f2bf(a.y);
        cv.t8[2] = f2bf(a.z); cv.t8[3] = f2bf(a.w);
        cv.t8[4] = f2bf(b.x); cv.t8[5] = f2bf(b.y);
        cv.t8[6] = f2bf(b.z); cv.t8[7] = f2bf(b.w);
        *(uint4*)(cvt_dst + g * 8) = cv.v;
      }
    }
    return;
  }

  int j = bid & 127, bh = bid >> 7;
  int tid = threadIdx.x, w = tid >> 6, l = tid & 63;
  int bq = w & 1, nh = w >> 1;
  int lr = l & 15, lg = l >> 4;

  const u16* aptr = h2_in + lg * 512 + (bh * 32 + bq * 16 + lr) * 8;
  const u16* bptr = W2 + (long)j * 32768 + lg * 256 + (nh * 16 + lr) * 8;

  int eb = tid >> 3, er = tid & 7;
  int gb = bh * 32 + eb, ecol = j * 8 + er;
  uint2 xv = *(const uint2*)(xprojT + ((long)t * 64 + gb) * 4096 + ecol * 4);
  float co = c_buf[gb * 1024 + ecol];

  f4v acc0 = {0.f, 0.f, 0.f, 0.f}, acc1 = {0.f, 0.f, 0.f, 0.f};
  f4v acc2 = {0.f, 0.f, 0.f, 0.f}, acc3 = {0.f, 0.f, 0.f, 0.f};
#pragma unroll
  for (int kc = 0; kc < 32; kc += 4) {
    s8v a0 = *(const s8v*)(aptr + (kc + 0) * 2048);
    s8v b0 = *(const s8v*)(bptr + (kc + 0) * 1024);
    s8v a1 = *(const s8v*)(aptr + (kc + 1) * 2048);
    s8v b1 = *(const s8v*)(bptr + (kc + 1) * 1024);
    s8v a2r = *(const s8v*)(aptr + (kc + 2) * 2048);
    s8v b2 = *(const s8v*)(bptr + (kc + 2) * 1024);
    s8v a3 = *(const s8v*)(aptr + (kc + 3) * 2048);
    s8v b3 = *(const s8v*)(bptr + (kc + 3) * 1024);
    acc0 = __builtin_amdgcn_mfma_f32_16x16x32_bf16(a0, b0, acc0, 0, 0, 0);
    acc1 = __builtin_amdgcn_mfma_f32_16x16x32_bf16(a1, b1, acc1, 0, 0, 0);
    acc2 = __builtin_amdgcn_mfma_f32_16x16x32_bf16(a2r, b2, acc2, 0, 0, 0);
    acc3 = __builtin_amdgcn_mfma_f32_16x16x32_bf16(a3, b3, acc3, 0, 0, 0);
  }
#pragma unroll
  for (int q = 0; q < 4; ++q)
    Gs[bq * 16 + lg * 4 + q][nh * 16 + lr] =
        acc0[q] + acc1[q] + acc2[q] + acc3[q];
  __syncthreads();

  float pi = Gs[eb][er]      + bf2f((u16)(xv.x));
  float pf = Gs[eb][8 + er]  + bf2f((u16)(xv.x >> 16));
  float pg = Gs[eb][16 + er] + bf2f((u16)(xv.y));
  float po = Gs[eb][24 + er] + bf2f((u16)(xv.y >> 16));
  float iv = 1.f / (1.f + expf(-pi));
  float fv = 1.f / (1.f + expf(-pf));
  float ov = 1.f / (1.f + expf(-po));
  float gv = tanhf(pg);
  float cn = fv * co + iv * gv;
  float hn = ov * tanhf(cn);
  c_buf[gb * 1024 + ecol] = cn;
  u16 hb = f2bf(hn);
  h2_next[j * 512 + bh * 256 + tid] = hb;   // H2 layout, contiguous per block
  a2[(long)(gb * 32 + t) * 3072 + ecol] = hb;
  if (t == 31) {
    hf[gb * 1024 + ecol] = hn;
    cf[gb * 1024 + ecol] = cn;
  }
}

// ---------------------------------------------------------------------------
// k_prep: ALL independent prep work in ONE launch (6976 blocks x 256 thr).
// ---------------------------------------------------------------------------
__global__ void k_prep(
    const float* __restrict__ bih, const float* __restrict__ bhh,
    const float* __restrict__ h0, const float* __restrict__ c0,
    const int* __restrict__ inputs, const float* __restrict__ emb,
    const float* __restrict__ enc, const float* __restrict__ Whh,
    const float* __restrict__ Wih, const float* __restrict__ combW,
    float* __restrict__ bias, u16* __restrict__ h2buf0,
    float* __restrict__ cbuf, u16* __restrict__ W2,
    u16* __restrict__ EMBX, u16* __restrict__ A2,
    u16* __restrict__ WIH_BF, u16* __restrict__ COMBW_BF, int haveW1) {
  int bid = blockIdx.x, tid = threadIdx.x;
  if (bid < 2048) {
    int idx = bid * 256 + tid;              // 524288 = 4096 rows x 128 s
    int row = idx >> 7, s = idx & 127;
    int g = row >> 10, rr = row & 1023;
    int j = rr >> 3, cc = rr & 7;
    const float* src = Whh + (long)row * 1024 + s * 8;
    float4 a = *(const float4*)src, b = *(const float4*)(src + 4);
    union { u16 t[8]; uint4 v; } cv;
    cv.t[0] = f2bf(a.x); cv.t[1] = f2bf(a.y); cv.t[2] = f2bf(a.z); cv.t[3] = f2bf(a.w);
    cv.t[4] = f2bf(b.x); cv.t[5] = f2bf(b.y); cv.t[6] = f2bf(b.z); cv.t[7] = f2bf(b.w);
    *(uint4*)(W2 + ((((long)j * 128 + s) * 32) + g * 8 + cc) * 8) = cv.v;
  } else if (bid < 4096) {
    if (!haveW1) return;
    int i = (bid - 2048) * 256 + tid;       // 524288 groups
    const float4* s = (const float4*)(Wih + (long)i * 8);
    float4 a = s[0], b = s[1];
    union { u16 t[8]; uint4 v; } cv;
    cv.t[0] = f2bf(a.x); cv.t[1] = f2bf(a.y); cv.t[2] = f2bf(a.z); cv.t[3] = f2bf(a.w);
    cv.t[4] = f2bf(b.x); cv.t[5] = f2bf(b.y); cv.t[6] = f2bf(b.z); cv.t[7] = f2bf(b.w);
    ((uint4*)WIH_BF)[i] = cv.v;
  } else if (bid < 5632) {
    if (!haveW1) return;
    int i = (bid - 4096) * 256 + tid;       // 393216 groups
    const float4* s = (const float4*)(combW + (long)i * 8);
    float4 a = s[0], b = s[1];
    union { u16 t[8]; uint4 v; } cv;
    cv.t[0] = f2bf(a.x); cv.t[1] = f2bf(a.y); cv.t[2] = f2bf(a.z); cv.t[3] = f2bf(a.w);
    cv.t[4] = f2bf(b.x); cv.t[5] = f2bf(b.y); cv.t[6] = f2bf(b.z); cv.t[7] = f2bf(b.w);
    ((uint4*)COMBW_BF)[i] = cv.v;
  } else if (bid < 6656) {
    int i = (bid - 5632) * 256 + tid;       // 262144 groups
    int r = i >> 7, k8 = (i & 127) * 8;
    const float* s = emb + (long)inputs[r] * 1024 + k8;
    float4 a = *(const float4*)s, b = *(const float4*)(s + 4);
    union { u16 t[8]; uint4 v; } cv;
    cv.t[0] = f2bf(a.x); cv.t[1] = f2bf(a.y); cv.t[2] = f2bf(a.z); cv.t[3] = f2bf(a.w);
    cv.t[4] = f2bf(b.x); cv.t[5] = f2bf(b.y); cv.t[6] = f2bf(b.z); cv.t[7] = f2bf(b.w);
    ((uint4*)EMBX)[i] = cv.v;
  } else if (bid < 6720) {
    int b = bid - 6656;                     // 64 batches
    int dg = tid;
    float s[8] = {0.f, 0.f, 0.f, 0.f, 0.f, 0.f, 0.f, 0.f};
    for (int si = 0; si < 64; ++si) {
      const float* p = enc + ((long)(b * 64 + si)) * 2048 + dg * 8;
      float4 x = *(const float4*)p, y = *(const float4*)(p + 4);
      s[0] += x.x; s[1] += x.y; s[2] += x.z; s[3] += x.w;
      s[4] += y.x; s[5] += y.y; s[6] += y.z; s[7] += y.w;
    }
    union { u16 t[8]; uint4 v; } cv;
#pragma unroll
    for (int e = 0; e < 8; ++e) cv.t[e] = f2bf(s[e]);
    for (int t2 = 0; t2 < 32; ++t2)
      *(uint4*)(A2 + (long)(b * 32 + t2) * 3072 + 1024 + dg * 8) = cv.v;
  } else {
    int i = (bid - 6720) * 256 + tid;       // 65536
    if (i < 4096) bias[i] = bih[i] + bhh[i];
    int b = i >> 10, col = i & 1023;
    h2buf0[(col >> 3) * 512 + b * 8 + (col & 7)] = f2bf(h0[i]);
    cbuf[i] = c0[i];
  }
}

// ---------------------------------------------------------------------------
extern "C" void kernel_launch(void* const* d_in, const int* in_sizes, int n_in,
                              void* d_out, int out_size, void* d_ws, size_t ws_size,
                              hipStream_t stream) {
  (void)in_sizes; (void)n_in; (void)out_size;
  const int*   inputs = (const int*)d_in[0];
  const float* enc    = (const float*)d_in[1];
  const float* h0     = (const float*)d_in[2];
  const float* c0     = (const float*)d_in[3];
  const float* emb    = (const float*)d_in[4];
  const float* Wih    = (const float*)d_in[5];
  const float* Whh    = (const float*)d_in[6];
  const float* bih    = (const float*)d_in[7];
  const float* bhh    = (const float*)d_in[8];
  // d_in[9] = attn_W: unused (softmax over size-1 axis == all ones)
  const float* combW  = (const float*)d_in[10];
  const float* combb  = (const float*)d_in[11];
  const float* outW   = (const float*)d_in[12];
  const float* outb   = (const float*)d_in[13];
  float* out = (float*)d_out;

  char* ws = (char*)d_ws;
  size_t off = 0;
  auto alloc = [&](size_t bytes) {
    char* p = ws + off;
    off += (bytes + 255) & ~(size_t)255;
    return p;
  };
  u16*   W2     = (u16*)  alloc(4096ull * 1024 * 2);   // Whh fragment layout
  u16*   XPROJ  = (u16*)  alloc(2048ull * 4096 * 2);   // [t][b][hcol][gate]
  u16*   EMBX   = (u16*)  alloc(2048ull * 1024 * 2);
  u16*   A2     = (u16*)  alloc(2048ull * 3072 * 2);
  u16*   OUTS   = (u16*)  alloc(2048ull * 1024 * 2);
  float* BIAS   = (float*)alloc(4096 * 4);
  u16*   H2BUF  = (u16*)  alloc(2ull * 65536 * 2);     // h ping-pong (H2 layout)
  float* CBUF   = (float*)alloc(65536 * 4);
  u16*   WIH_BF   = (u16*)alloc(4096ull * 1024 * 2);
  u16*   COMBW_BF = (u16*)alloc(1024ull * 3072 * 2);
  size_t off_w1 = off;
  u16*   OUTW_BF  = (u16*)alloc(32000ull * 1024 * 2);
  size_t off_w2 = off;                                 // ~127 MB
  bool haveW1 = ws_size >= off_w1;
  bool haveW2 = ws_size >= off_w2;

  // ONE fused prep launch (Whh/Wih/combW converts, emb, ctx, bias/h0/c0)
  k_prep<<<dim3(6976), dim3(256), 0, stream>>>(
      bih, bhh, h0, c0, inputs, emb, enc, Whh, Wih, combW,
      BIAS, H2BUF, CBUF, W2, EMBX, A2, WIH_BF, COMBW_BF, haveW1 ? 1 : 0);

  // GEMM1: XPROJ (permuted layout) = EMBX @ W_ih^T + (b_ih+b_hh)
  if (haveW1)
    gemm_p<1, 1><<<dim3(256), dim3(512), 0, stream>>>(EMBX, WIH_BF, BIAS, XPROJ,
                                                      1024, 4096, 16);
  else
    gemm_btf<1, 1><<<dim3(512), dim3(256), 0, stream>>>(EMBX, Wih, BIAS, XPROJ,
                                                        1024, 4096, 16);

  // 32 sequential LSTM steps; blocks 256..511 convert outW slice t
  for (int t = 0; t < 32; ++t) {
    u16* hin  = H2BUF + (t & 1) * 65536;
    u16* hout = H2BUF + ((t + 1) & 1) * 65536;
    lstm_step5<<<dim3(512), dim3(256), 0, stream>>>(
        W2, XPROJ, hin, hout, CBUF, A2,
        out + 65536000, out + 65536000 + 65536, t,
        outW, OUTW_BF, t * 128000, haveW2 ? 128000 : 0);
  }

  // GEMM2: OUTS = tanh([h_seq|ctx] @ comb_W^T + comb_b)  (K=3072, BN=64)
  if (haveW1)
    gemm_s<2, 2><<<dim3(256), dim3(256), 0, stream>>>(A2, COMBW_BF, combb, OUTS,
                                                      3072, 1024, 16);
  else
    gemm_btf<2, 0><<<dim3(128), dim3(256), 0, stream>>>(A2, combW, combb, OUTS,
                                                        3072, 1024, 16);
  // GEMM3: logits = OUTS @ out_W^T + out_b  (128x128, 4 blocks/CU)
  if (haveW2)
    gemm_s<3, 4><<<dim3(4000), dim3(256), 0, stream>>>(OUTS, OUTW_BF, outb, d_out,
                                                       1024, 32000, 16);
  else
    gemm_btf<3, 0><<<dim3(4000), dim3(256), 0, stream>>>(OUTS, outW, outb, d_out,
                                                         1024, 32000, 16);
}